// Round 2
// baseline (3724.906 us; speedup 1.0000x reference)
//
#include <hip/hip_runtime.h>
#include <math.h>

#define HID 51
#define TMAIN 1024
#define FUT 64
#define TT (TMAIN + FUT)
#define NQ 13  // 13 float4 = 52 floats per gate row (k=51 padded with 0)

__device__ __forceinline__ float fast_sigmoid(float x) {
  return 1.0f / (1.0f + __expf(-x));
}
__device__ __forceinline__ float fast_tanh(float x) {
  return 1.0f - 2.0f / (__expf(2.0f * x) + 1.0f);
}

// acc0..acc3 += wq[g][:] . hbuf[:]   (52 floats; slots 51..53 are zero-padded
// on BOTH sides so the extra lanes contribute exactly 0)
#define DOT_ROWS(hbuf)                                  \
  {                                                     \
    const float4* h4 = (const float4*)(hbuf);           \
    _Pragma("unroll") for (int q = 0; q < NQ; ++q) {    \
      float4 hv = h4[q];                                \
      acc0 = fmaf(hv.x, wq[0][q].x, acc0);              \
      acc0 = fmaf(hv.y, wq[0][q].y, acc0);              \
      acc0 = fmaf(hv.z, wq[0][q].z, acc0);              \
      acc0 = fmaf(hv.w, wq[0][q].w, acc0);              \
      acc1 = fmaf(hv.x, wq[1][q].x, acc1);              \
      acc1 = fmaf(hv.y, wq[1][q].y, acc1);              \
      acc1 = fmaf(hv.z, wq[1][q].z, acc1);              \
      acc1 = fmaf(hv.w, wq[1][q].w, acc1);              \
      acc2 = fmaf(hv.x, wq[2][q].x, acc2);              \
      acc2 = fmaf(hv.y, wq[2][q].y, acc2);              \
      acc2 = fmaf(hv.z, wq[2][q].z, acc2);              \
      acc2 = fmaf(hv.w, wq[2][q].w, acc2);              \
      acc3 = fmaf(hv.x, wq[3][q].x, acc3);              \
      acc3 = fmaf(hv.y, wq[3][q].y, acc3);              \
      acc3 = fmaf(hv.z, wq[3][q].z, acc3);              \
      acc3 = fmaf(hv.w, wq[3][q].w, acc3);              \
    }                                                   \
  }

// One block = one batch element. 3 waves:
//   wave 0: W_hh1 rows (layer-1 recurrent) + layer-1 cell (c1 in regs)
//   wave 1: W_hh2 rows (layer-2 recurrent partial)
//   wave 2: W_ih2 rows (layer-2 input) + layer-2 cell (c2 in regs) + linear
// Lane j (j<51) holds the i/f/g/o rows of hidden unit j: 4x13 float4 = 208
// VGPRs of weights. launch_bounds(192,1): VGPR cap 512 so they MUST NOT spill
// (R1 post-mortem: (192,2) gave VGPR_Count=128 + scratch spill, 2980us).
__global__ __launch_bounds__(192, 1)
void lstm2_persistent(const float* __restrict__ input,
                      const float* __restrict__ Wi1,
                      const float* __restrict__ Wh1,
                      const float* __restrict__ bi1,
                      const float* __restrict__ bh1,
                      const float* __restrict__ Wi2,
                      const float* __restrict__ Wh2,
                      const float* __restrict__ bi2,
                      const float* __restrict__ bh2,
                      const float* __restrict__ Wlin,
                      const float* __restrict__ blin,
                      float* __restrict__ out) {
  __shared__ __align__(16) float lds_x[TMAIN];
  __shared__ __align__(16) float lds_h1[64];
  __shared__ __align__(16) float lds_h2[64];
  __shared__ __align__(16) float lds_p2[4][64];
  __shared__ float lds_fb[1];

  const int b = blockIdx.x;
  const int tid = threadIdx.x;
  const int wid = tid >> 6;
  const int lane = tid & 63;
  const bool act = lane < HID;
  const int j = act ? lane : 0;  // clamped row index for inactive lanes

  for (int i = tid; i < TMAIN; i += 192) lds_x[i] = input[b * TMAIN + i];
  if (tid < 64) {
    lds_h1[tid] = 0.0f;  // slots 51..63 stay 0 forever (pad correctness)
    lds_h2[tid] = 0.0f;
  }

  // ---- Per-lane weight rows -> registers (constant-indexed float4 array) ----
  float4 wq[4][NQ];
  float bias[4] = {0.f, 0.f, 0.f, 0.f};
  float wi1g[4] = {0.f, 0.f, 0.f, 0.f};
  float wlin_j = 0.0f;
  float c_state = 0.0f;

  const float* Wsel = (wid == 0) ? Wh1 : ((wid == 1) ? Wh2 : Wi2);
#pragma unroll
  for (int g = 0; g < 4; ++g) {
    const float* row = Wsel + (g * HID + j) * HID;
#pragma unroll
    for (int q = 0; q < NQ; ++q) {
      float4 v;
      v.x = (4 * q + 0 < HID) ? row[4 * q + 0] : 0.0f;
      v.y = (4 * q + 1 < HID) ? row[4 * q + 1] : 0.0f;
      v.z = (4 * q + 2 < HID) ? row[4 * q + 2] : 0.0f;
      v.w = (4 * q + 3 < HID) ? row[4 * q + 3] : 0.0f;
      wq[g][q] = v;
    }
  }
  if (wid == 0) {
#pragma unroll
    for (int g = 0; g < 4; ++g) {
      bias[g] = bi1[g * HID + j] + bh1[g * HID + j];
      wi1g[g] = Wi1[g * HID + j];
    }
  } else if (wid == 2) {
#pragma unroll
    for (int g = 0; g < 4; ++g) bias[g] = bi2[g * HID + j] + bh2[g * HID + j];
    wlin_j = Wlin[j];
  }
  const float blin_s = blin[0];

  __syncthreads();

  for (int t = 0; t < TT; ++t) {
    // ---------------- phase 1 ----------------
    if (wid == 0) {
      float x = (t < TMAIN) ? lds_x[t] : lds_fb[0];
      float acc0 = fmaf(x, wi1g[0], bias[0]);
      float acc1 = fmaf(x, wi1g[1], bias[1]);
      float acc2 = fmaf(x, wi1g[2], bias[2]);
      float acc3 = fmaf(x, wi1g[3], bias[3]);
      DOT_ROWS(lds_h1);
      float gi = fast_sigmoid(acc0);
      float gf = fast_sigmoid(acc1);
      float gg = fast_tanh(acc2);
      float go = fast_sigmoid(acc3);
      c_state = gf * c_state + gi * gg;
      float h = go * fast_tanh(c_state);
      if (act) lds_h1[lane] = h;  // intra-wave: all reads precede this write
    } else if (wid == 1) {
      float acc0 = 0.f, acc1 = 0.f, acc2 = 0.f, acc3 = 0.f;
      DOT_ROWS(lds_h2);
      if (act) {
        lds_p2[0][lane] = acc0;
        lds_p2[1][lane] = acc1;
        lds_p2[2][lane] = acc2;
        lds_p2[3][lane] = acc3;
      }
    }
    __syncthreads();  // h1_new + p2 visible

    // ---------------- phase 2 ----------------
    if (wid == 2) {
      float acc0 = bias[0] + lds_p2[0][j];
      float acc1 = bias[1] + lds_p2[1][j];
      float acc2 = bias[2] + lds_p2[2][j];
      float acc3 = bias[3] + lds_p2[3][j];
      DOT_ROWS(lds_h1);  // Wi2 @ h1_new
      float gi = fast_sigmoid(acc0);
      float gf = fast_sigmoid(acc1);
      float gg = fast_tanh(acc2);
      float go = fast_sigmoid(acc3);
      c_state = gf * c_state + gi * gg;
      float h = go * fast_tanh(c_state);
      float val = 0.0f;
      if (act) {
        lds_h2[lane] = h;
        val = wlin_j * h;
      }
#pragma unroll
      for (int off = 32; off >= 1; off >>= 1) val += __shfl_xor(val, off);
      if (lane == 0) {
        float o = val + blin_s;
        out[b * TT + t] = o;
        lds_fb[0] = o;  // feedback input for the future phase
      }
    }
    __syncthreads();  // h2_new + fb visible for next timestep
  }
}

extern "C" void kernel_launch(void* const* d_in, const int* in_sizes, int n_in,
                              void* d_out, int out_size, void* d_ws,
                              size_t ws_size, hipStream_t stream) {
  const float* input = (const float*)d_in[0];
  const float* Wi1 = (const float*)d_in[1];
  const float* Wh1 = (const float*)d_in[2];
  const float* bi1 = (const float*)d_in[3];
  const float* bh1 = (const float*)d_in[4];
  const float* Wi2 = (const float*)d_in[5];
  const float* Wh2 = (const float*)d_in[6];
  const float* bi2 = (const float*)d_in[7];
  const float* bh2 = (const float*)d_in[8];
  const float* Wlin = (const float*)d_in[9];
  const float* blin = (const float*)d_in[10];
  float* out = (float*)d_out;

  const int B = in_sizes[0] / TMAIN;  // 512
  lstm2_persistent<<<B, 192, 0, stream>>>(input, Wi1, Wh1, bi1, bh1, Wi2, Wh2,
                                          bi2, bh2, Wlin, blin, out);
}

// Round 3
// 3693.472 us; speedup vs baseline: 1.0085x; 1.0085x over previous
//
#include <hip/hip_runtime.h>
#include <math.h>

#define HID 51
#define TMAIN 1024
#define FUT 64
#define TT (TMAIN + FUT)
#define NQ 13  // 13 float4 = 52 floats per gate row (k=51 padded with 0)

__device__ __forceinline__ float fast_sigmoid(float x) {
  return 1.0f / (1.0f + __expf(-x));
}
__device__ __forceinline__ float fast_tanh(float x) {
  return 1.0f - 2.0f / (__expf(2.0f * x) + 1.0f);
}

// Pin a float4's components into VGPRs via an opaque asm def. The register
// allocator cannot REMATERIALIZE an asm output (R2 post-mortem: without this,
// the RA re-issued the weight global_loads inside the timestep loop every
// iteration -> latency-bound, VGPR_Count=144, 3725us).
#define PIN4(v)                                                        \
  asm volatile("" : "+v"((v).x), "+v"((v).y), "+v"((v).z), "+v"((v).w))

// acc0..acc3 += wq[g][:] . hbuf[:]   (52 floats; slots 51..53 zero-padded on
// BOTH sides so the pad lanes contribute exactly 0)
#define DOT_ROWS(hbuf)                                  \
  {                                                     \
    const float4* h4 = (const float4*)(hbuf);           \
    _Pragma("unroll") for (int q = 0; q < NQ; ++q) {    \
      float4 hv = h4[q];                                \
      acc0 = fmaf(hv.x, wq[0][q].x, acc0);              \
      acc0 = fmaf(hv.y, wq[0][q].y, acc0);              \
      acc0 = fmaf(hv.z, wq[0][q].z, acc0);              \
      acc0 = fmaf(hv.w, wq[0][q].w, acc0);              \
      acc1 = fmaf(hv.x, wq[1][q].x, acc1);              \
      acc1 = fmaf(hv.y, wq[1][q].y, acc1);              \
      acc1 = fmaf(hv.z, wq[1][q].z, acc1);              \
      acc1 = fmaf(hv.w, wq[1][q].w, acc1);              \
      acc2 = fmaf(hv.x, wq[2][q].x, acc2);              \
      acc2 = fmaf(hv.y, wq[2][q].y, acc2);              \
      acc2 = fmaf(hv.z, wq[2][q].z, acc2);              \
      acc2 = fmaf(hv.w, wq[2][q].w, acc2);              \
      acc3 = fmaf(hv.x, wq[3][q].x, acc3);              \
      acc3 = fmaf(hv.y, wq[3][q].y, acc3);              \
      acc3 = fmaf(hv.z, wq[3][q].z, acc3);              \
      acc3 = fmaf(hv.w, wq[3][q].w, acc3);              \
    }                                                   \
  }

// One block = one batch element. 3 waves:
//   wave 0: W_hh1 rows (layer-1 recurrent) + layer-1 cell (c1 in regs)
//   wave 1: W_hh2 rows (layer-2 recurrent partial)
//   wave 2: W_ih2 rows (layer-2 input) + layer-2 cell (c2 in regs) + linear
// Lane j (j<51) holds the i/f/g/o rows of hidden unit j: 4x13 float4 = 208
// VGPRs of weights, pinned via PIN4. launch_bounds(192,1): 512-VGPR budget.
__global__ __launch_bounds__(192, 1)
void lstm2_persistent(const float* __restrict__ input,
                      const float* __restrict__ Wi1,
                      const float* __restrict__ Wh1,
                      const float* __restrict__ bi1,
                      const float* __restrict__ bh1,
                      const float* __restrict__ Wi2,
                      const float* __restrict__ Wh2,
                      const float* __restrict__ bi2,
                      const float* __restrict__ bh2,
                      const float* __restrict__ Wlin,
                      const float* __restrict__ blin,
                      float* __restrict__ out) {
  __shared__ __align__(16) float lds_x[TMAIN];
  __shared__ __align__(16) float lds_h1[64];
  __shared__ __align__(16) float lds_h2[64];
  __shared__ __align__(16) float lds_p2[4][64];
  __shared__ float lds_fb[1];

  const int b = blockIdx.x;
  const int tid = threadIdx.x;
  const int wid = tid >> 6;
  const int lane = tid & 63;
  const bool act = lane < HID;
  const int j = act ? lane : 0;  // clamped row index for inactive lanes

  for (int i = tid; i < TMAIN; i += 192) lds_x[i] = input[b * TMAIN + i];
  if (tid < 64) {
    lds_h1[tid] = 0.0f;  // slots 51..63 stay 0 forever (pad correctness)
    lds_h2[tid] = 0.0f;
  }

  // ---- Per-lane weight rows -> registers, pinned against remat ----
  float4 wq[4][NQ];
  float bias[4] = {0.f, 0.f, 0.f, 0.f};
  float wi1g[4] = {0.f, 0.f, 0.f, 0.f};
  float wlin_j = 0.0f;
  float c_state = 0.0f;

  const float* Wsel = (wid == 0) ? Wh1 : ((wid == 1) ? Wh2 : Wi2);
#pragma unroll
  for (int g = 0; g < 4; ++g) {
    const float* row = Wsel + (g * HID + j) * HID;
#pragma unroll
    for (int q = 0; q < NQ; ++q) {
      float4 v;
      v.x = (4 * q + 0 < HID) ? row[4 * q + 0] : 0.0f;
      v.y = (4 * q + 1 < HID) ? row[4 * q + 1] : 0.0f;
      v.z = (4 * q + 2 < HID) ? row[4 * q + 2] : 0.0f;
      v.w = (4 * q + 3 < HID) ? row[4 * q + 3] : 0.0f;
      PIN4(v);  // opaque def: cannot be remat'd back to a global load
      wq[g][q] = v;
    }
  }
  if (wid == 0) {
#pragma unroll
    for (int g = 0; g < 4; ++g) {
      bias[g] = bi1[g * HID + j] + bh1[g * HID + j];
      wi1g[g] = Wi1[g * HID + j];
    }
  } else if (wid == 2) {
#pragma unroll
    for (int g = 0; g < 4; ++g) bias[g] = bi2[g * HID + j] + bh2[g * HID + j];
    wlin_j = Wlin[j];
  }
  const float blin_s = blin[0];

  __syncthreads();

  for (int t = 0; t < TT; ++t) {
    // ---------------- phase 1 ----------------
    if (wid == 0) {
      float x = (t < TMAIN) ? lds_x[t] : lds_fb[0];
      float acc0 = fmaf(x, wi1g[0], bias[0]);
      float acc1 = fmaf(x, wi1g[1], bias[1]);
      float acc2 = fmaf(x, wi1g[2], bias[2]);
      float acc3 = fmaf(x, wi1g[3], bias[3]);
      DOT_ROWS(lds_h1);
      float gi = fast_sigmoid(acc0);
      float gf = fast_sigmoid(acc1);
      float gg = fast_tanh(acc2);
      float go = fast_sigmoid(acc3);
      c_state = gf * c_state + gi * gg;
      float h = go * fast_tanh(c_state);
      if (act) lds_h1[lane] = h;  // intra-wave: all reads precede this write
    } else if (wid == 1) {
      float acc0 = 0.f, acc1 = 0.f, acc2 = 0.f, acc3 = 0.f;
      DOT_ROWS(lds_h2);
      if (act) {
        lds_p2[0][lane] = acc0;
        lds_p2[1][lane] = acc1;
        lds_p2[2][lane] = acc2;
        lds_p2[3][lane] = acc3;
      }
    }
    __syncthreads();  // h1_new + p2 visible

    // ---------------- phase 2 ----------------
    if (wid == 2) {
      float acc0 = bias[0] + lds_p2[0][j];
      float acc1 = bias[1] + lds_p2[1][j];
      float acc2 = bias[2] + lds_p2[2][j];
      float acc3 = bias[3] + lds_p2[3][j];
      DOT_ROWS(lds_h1);  // Wi2 @ h1_new
      float gi = fast_sigmoid(acc0);
      float gf = fast_sigmoid(acc1);
      float gg = fast_tanh(acc2);
      float go = fast_sigmoid(acc3);
      c_state = gf * c_state + gi * gg;
      float h = go * fast_tanh(c_state);
      float val = 0.0f;
      if (act) {
        lds_h2[lane] = h;
        val = wlin_j * h;
      }
#pragma unroll
      for (int off = 32; off >= 1; off >>= 1) val += __shfl_xor(val, off);
      if (lane == 0) {
        float o = val + blin_s;
        out[b * TT + t] = o;
        lds_fb[0] = o;  // feedback input for the future phase
      }
    }
    __syncthreads();  // h2_new + fb visible for next timestep
  }
}

extern "C" void kernel_launch(void* const* d_in, const int* in_sizes, int n_in,
                              void* d_out, int out_size, void* d_ws,
                              size_t ws_size, hipStream_t stream) {
  const float* input = (const float*)d_in[0];
  const float* Wi1 = (const float*)d_in[1];
  const float* Wh1 = (const float*)d_in[2];
  const float* bi1 = (const float*)d_in[3];
  const float* bh1 = (const float*)d_in[4];
  const float* Wi2 = (const float*)d_in[5];
  const float* Wh2 = (const float*)d_in[6];
  const float* bi2 = (const float*)d_in[7];
  const float* bh2 = (const float*)d_in[8];
  const float* Wlin = (const float*)d_in[9];
  const float* blin = (const float*)d_in[10];
  float* out = (float*)d_out;

  const int B = in_sizes[0] / TMAIN;  // 512
  lstm2_persistent<<<B, 192, 0, stream>>>(input, Wi1, Wh1, bi1, bh1, Wi2, Wh2,
                                          bi2, bh2, Wlin, blin, out);
}

// Round 4
// 3106.744 us; speedup vs baseline: 1.1990x; 1.1889x over previous
//
#include <hip/hip_runtime.h>
#include <math.h>

#define HID 51
#define NROW 204  // 4*HID, torch gate order [i|f|g|o]
#define TMAIN 1024
#define FUT 64
#define TT (TMAIN + FUT)

__device__ __forceinline__ float fast_sigmoid(float x) {
  return 1.0f / (1.0f + __expf(-x));
}
__device__ __forceinline__ float fast_tanh(float x) {
  return 1.0f - 2.0f / (__expf(2.0f * x) + 1.0f);
}

// Opaque def: result of asm cannot be rematerialized from the global load.
#define PIN4(v) asm("" : "+v"((v).x), "+v"((v).y), "+v"((v).z), "+v"((v).w))

// Load float4 #q of a 51-float row; q is a literal so the tail guards fold.
__device__ __forceinline__ float4 load_q(const float* row, int q) {
  float4 v;
  v.x = (4 * q + 0 < HID) ? row[4 * q + 0] : 0.0f;
  v.y = (4 * q + 1 < HID) ? row[4 * q + 1] : 0.0f;
  v.z = (4 * q + 2 < HID) ? row[4 * q + 2] : 0.0f;
  v.w = (4 * q + 3 < HID) ? row[4 * q + 3] : 0.0f;
  return v;
}

#define QLIST(F) F(0) F(1) F(2) F(3) F(4) F(5) F(6) F(7) F(8) F(9) F(10) F(11) F(12)

// NAMED float4 locals — no array, no alloca, guaranteed SSA (R1-R3 post-mortem:
// float w[4][51] / float4 wq[4][13] never got promoted; VGPR stuck at 128-144
// and the K-loop re-read weights from memory every timestep).
#define DECL_LOAD(q)                          \
  float4 wa##q = load_q(rowA, q); PIN4(wa##q); \
  float4 wb##q = load_q(rowB, q); PIN4(wb##q); \
  float4 wc##q = load_q(rowC, q); PIN4(wc##q);

// S1: two independent dots (8 accumulators of ILP): Wh1[t].h1  and  Wh2[t].h2
#define S1_Q(q) {                              \
    float4 hv1 = h1v[q];                       \
    float4 hv2 = h2v[q];                       \
    acc1.x = fmaf(hv1.x, wa##q.x, acc1.x);     \
    acc1.y = fmaf(hv1.y, wa##q.y, acc1.y);     \
    acc1.z = fmaf(hv1.z, wa##q.z, acc1.z);     \
    acc1.w = fmaf(hv1.w, wa##q.w, acc1.w);     \
    acc2.x = fmaf(hv2.x, wb##q.x, acc2.x);     \
    acc2.y = fmaf(hv2.y, wb##q.y, acc2.y);     \
    acc2.z = fmaf(hv2.z, wb##q.z, acc2.z);     \
    acc2.w = fmaf(hv2.w, wb##q.w, acc2.w); }

// S3: Wi2[t].h1_new
#define S3_Q(q) {                              \
    float4 hv = h1v[q];                        \
    acc3.x = fmaf(hv.x, wc##q.x, acc3.x);      \
    acc3.y = fmaf(hv.y, wc##q.y, acc3.y);      \
    acc3.z = fmaf(hv.z, wc##q.z, acc3.z);      \
    acc3.w = fmaf(hv.w, wc##q.w, acc3.w); }

// One block = one batch element. Thread t<204 owns gate-row t of Wh1, Wh2 and
// Wi2 (3x13 named float4 = 156 weight VGPRs). p2 (layer-2 recurrent partial)
// never leaves the thread's registers. Threads 0..50 additionally own c1,c2.
// 4 waves/block, <=256 VGPR (launch_bounds(256,2)) -> 2 blocks/CU -> all 512
// blocks co-resident in one generation.
__global__ __launch_bounds__(256, 2)
void lstm2_persistent(const float* __restrict__ input,
                      const float* __restrict__ Wi1,
                      const float* __restrict__ Wh1,
                      const float* __restrict__ bi1,
                      const float* __restrict__ bh1,
                      const float* __restrict__ Wi2,
                      const float* __restrict__ Wh2,
                      const float* __restrict__ bi2,
                      const float* __restrict__ bh2,
                      const float* __restrict__ Wlin,
                      const float* __restrict__ blin,
                      float* __restrict__ out) {
  __shared__ __align__(16) float lds_x[TMAIN];
  __shared__ __align__(16) float lds_h1[64];  // slots 51..63 stay 0 (pad)
  __shared__ __align__(16) float lds_h2[64];
  __shared__ __align__(16) float lds_a1[NROW];
  __shared__ __align__(16) float lds_a2[NROW];
  __shared__ float lds_fb;

  const int b = blockIdx.x;
  const int t = threadIdx.x;
  const bool rowact = t < NROW;
  const int r = rowact ? t : 0;  // clamped row index for idle lanes

  for (int i = t; i < TMAIN; i += 256) lds_x[i] = input[b * TMAIN + i];
  if (t < 64) {
    lds_h1[t] = 0.0f;
    lds_h2[t] = 0.0f;
  }

  const float* rowA = Wh1 + r * HID;
  const float* rowB = Wh2 + r * HID;
  const float* rowC = Wi2 + r * HID;
  QLIST(DECL_LOAD)

  const float b1s = bi1[r] + bh1[r];
  const float b2s = bi2[r] + bh2[r];
  const float wi1r = Wi1[r];
  const float wlin_t = (t < HID) ? Wlin[t] : 0.0f;
  const float blin_s = blin[0];
  float c1 = 0.0f, c2 = 0.0f;
  float p2 = 0.0f;

  __syncthreads();

  const float4* h1v = (const float4*)lds_h1;
  const float4* h2v = (const float4*)lds_h2;

  for (int step = 0; step < TT; ++step) {
    // ---- S1: a1[t] = Wh1[t].h1 + x*Wi1[t] + b1 ; p2 = Wh2[t].h2 (in reg) ----
    {
      float x = (step < TMAIN) ? lds_x[step] : lds_fb;
      float4 acc1 = {0.f, 0.f, 0.f, 0.f};
      float4 acc2 = {0.f, 0.f, 0.f, 0.f};
      QLIST(S1_Q)
      float a1 = (acc1.x + acc1.y) + (acc1.z + acc1.w) + fmaf(x, wi1r, b1s);
      p2 = (acc2.x + acc2.y) + (acc2.z + acc2.w);
      if (rowact) lds_a1[t] = a1;
    }
    __syncthreads();

    // ---- S2: layer-1 cell update (c1 in regs of threads 0..50) ----
    if (t < HID) {
      float gi = fast_sigmoid(lds_a1[t]);
      float gf = fast_sigmoid(lds_a1[HID + t]);
      float gg = fast_tanh(lds_a1[2 * HID + t]);
      float go = fast_sigmoid(lds_a1[3 * HID + t]);
      c1 = gf * c1 + gi * gg;
      lds_h1[t] = go * fast_tanh(c1);
    }
    __syncthreads();

    // ---- S3: a2[t] = Wi2[t].h1_new + p2 + b2 ----
    {
      float4 acc3 = {0.f, 0.f, 0.f, 0.f};
      QLIST(S3_Q)
      float a2 = (acc3.x + acc3.y) + (acc3.z + acc3.w) + p2 + b2s;
      if (rowact) lds_a2[t] = a2;
    }
    __syncthreads();

    // ---- S4: layer-2 cell + linear head (wave 0) ----
    if (t < 64) {
      float val = 0.0f;
      if (t < HID) {
        float gi = fast_sigmoid(lds_a2[t]);
        float gf = fast_sigmoid(lds_a2[HID + t]);
        float gg = fast_tanh(lds_a2[2 * HID + t]);
        float go = fast_sigmoid(lds_a2[3 * HID + t]);
        c2 = gf * c2 + gi * gg;
        float h2n = go * fast_tanh(c2);
        lds_h2[t] = h2n;
        val = wlin_t * h2n;
      }
#pragma unroll
      for (int off = 32; off >= 1; off >>= 1) val += __shfl_xor(val, off);
      if (t == 0) {
        float o = val + blin_s;
        out[b * TT + step] = o;
        lds_fb = o;  // feedback input for the future phase
      }
    }
    __syncthreads();  // h2_new + fb visible for next step's S1
  }
}

extern "C" void kernel_launch(void* const* d_in, const int* in_sizes, int n_in,
                              void* d_out, int out_size, void* d_ws,
                              size_t ws_size, hipStream_t stream) {
  const float* input = (const float*)d_in[0];
  const float* Wi1 = (const float*)d_in[1];
  const float* Wh1 = (const float*)d_in[2];
  const float* bi1 = (const float*)d_in[3];
  const float* bh1 = (const float*)d_in[4];
  const float* Wi2 = (const float*)d_in[5];
  const float* Wh2 = (const float*)d_in[6];
  const float* bi2 = (const float*)d_in[7];
  const float* bh2 = (const float*)d_in[8];
  const float* Wlin = (const float*)d_in[9];
  const float* blin = (const float*)d_in[10];
  float* out = (float*)d_out;

  const int B = in_sizes[0] / TMAIN;  // 512
  lstm2_persistent<<<B, 256, 0, stream>>>(input, Wi1, Wh1, bi1, bh1, Wi2, Wh2,
                                          bi2, bh2, Wlin, blin, out);
}